// Round 7
// baseline (1493.530 us; speedup 1.0000x reference)
//
#include <hip/hip_runtime.h>

// Forward bilinear warp (splat) -- tile-local BIN + GATHER formulation.
//   im0:  [B, C, H, W] fp32 ; flow: [B, H, W, 2] fp32 ; out: [B, C, H, W] fp32
//
// Rounds 0-4: splat loop was LDS-fp-atomic-throughput-bound -> replaced with
// bin (1 int atomic/pixel) + per-cell register gather (round 5: 1181->848us).
// Round 5 counters: VALU 31%, HBM 8%, occupancy 40% (1 block/CU from 147KB
// LDS) -> latency-bound on the scattered-load chain in the gather phase.
// THIS ROUND: shrink LDS to 81,228 B (K=4, 95x95 bins, byte-packed counts)
// -> 2 blocks/CU = 32 waves/CU, doubling latency hiding. Structure otherwise
// unchanged. Core cells -> plain store; halo -> buffer + hgather pass;
// window-miss pixels -> far kernel; bin-overflow pixels -> replay kernel.

#define TS   80
#define R    8
#define WIN  96             // TS + 2R
#define CG   4              // channels per block
#define NCG  8              // C / CG
#define NT1  1024
#define TILES_X 11          // ceil(854/80)
#define TILES_Y 6           // 480/80
#define NTILES (TILES_X * TILES_Y)
#define HALO_CELLS 2816     // WIN*WIN - TS*TS
#define NBX  (WIN - 1)      // 95: NW corner local coord range [0, TS+2R-2]
#define NBIN (NBX * NBX)    // 9025 bins
#define K    4              // bin capacity; overflow -> replay kernel
#define CNTW ((NBIN + 3) / 4)  // byte-packed counts, 4 cells per u32
#define B_  4
#define C_  32
#define H_  480
#define W_  854
#define HW_ (H_ * W_)

__device__ __forceinline__ void fadd_glb(float* p, float v) { unsafeAtomicAdd(p, v); }

// halo strip layout: [0,768): top R x WIN ; [768,1536): bottom R x WIN ;
// [1536,2176): left TS x R ; [2176,2816): right TS x R
__device__ __forceinline__ int halo_cell(int wy, int wx) {
    if (wy < R)       return wy * WIN + wx;
    if (wy >= TS + R) return R * WIN + (wy - (TS + R)) * WIN + wx;
    if (wx < R)       return 2 * R * WIN + (wy - R) * R + wx;
    return 2 * R * WIN + TS * R + (wy - R) * R + (wx - (TS + R));
}

__global__ __launch_bounds__(NT1)
void fw_warp_bin(const float* __restrict__ im0,
                 const float* __restrict__ flow,
                 float* __restrict__ out,
                 float* __restrict__ buf,
                 unsigned* __restrict__ ovctr,
                 unsigned* __restrict__ ovlist,
                 unsigned cap) {
    __shared__ unsigned short bins[NBIN * K];   // 72,200 B
    __shared__ unsigned       cntp[CNTW];       //  9,028 B  (total 81,228 -> 2 blk/CU)

    const int cg = blockIdx.x;              // channel group 0..7
    const int tI = blockIdx.y;              // tile 0..65
    const int b  = blockIdx.z;
    const int tx0 = (tI % TILES_X) * TS;
    const int ty0 = (tI / TILES_X) * TS;
    const int tid = threadIdx.x;

    for (int i = tid; i < CNTW; i += NT1) cntp[i] = 0u;
    __syncthreads();

    const float*  imp = im0 + (size_t)(b * C_ + cg * CG) * HW_;
    const float2* flp = (const float2*)flow + (size_t)b * HW_;

    // ---- phase 1: bin pixels by NW corner cell (1 int atomic per pixel) ----
    for (int i = tid; i < TS * TS; i += NT1) {
        int py = i / TS, px = i - py * TS;
        int y = ty0 + py, x = tx0 + px;
        if (x >= W_) continue;              // partial right-edge tile
        float2 f = flp[y * W_ + x];
        float xf = (float)x + f.x;
        float yf = (float)y + f.y;
        float x0f = floorf(xf), y0f = floorf(yf);
        int x0 = (int)x0f, y0 = (int)y0f;
        // both corners must be inside the LDS window (same predicate as far)
        if (x0 < tx0 - R || x0 > tx0 + TS + R - 2 ||
            y0 < ty0 - R || y0 > ty0 + TS + R - 2) continue;   // far kernel
        int bin = (y0 - (ty0 - R)) * NBX + (x0 - (tx0 - R));   // [0, NBIN)
        unsigned sh = (unsigned)(bin & 3) * 8u;
        unsigned old = atomicAdd(&cntp[bin >> 2], 1u << sh);   // ds_add_rtn_u32
        unsigned slot = (old >> sh) & 0xFFu;                   // byte count < 255 for
        if (slot < K) {                                        // continuous random flow
            bins[bin * K + slot] = (unsigned short)i;
        } else {
            // overflow: replay later with global atomics (per-cg entry so all
            // 8 cg-blocks stay consistent despite order-dependent slots)
            unsigned gid = (unsigned)(b * HW_ + y * W_ + x);    // < 2^24
            unsigned idx = atomicAdd(ovctr, 1u);
            if (idx < cap) ovlist[idx] = ((unsigned)cg << 24) | gid;
        }
    }
    __syncthreads();

    // ---- phase 2: per-cell gather + direct flush ----
    float* outp = out + (size_t)(b * C_ + cg * CG) * HW_;
    float* bufp = buf + ((size_t)(b * C_ + cg * CG) * NTILES + tI) * HALO_CELLS;
    for (int i = tid; i < WIN * WIN; i += NT1) {
        int wy = i / WIN, wx = i - wy * WIN;
        float s0 = 0.f, s1 = 0.f, s2 = 0.f, s3 = 0.f;
        #pragma unroll
        for (int a = 0; a < 2; ++a) {           // NW row: wy-a
            int by = wy - a;
            if ((unsigned)by >= (unsigned)NBX) continue;
            #pragma unroll
            for (int bxo = 0; bxo < 2; ++bxo) { // NW col: wx-bxo
                int bx = wx - bxo;
                if ((unsigned)bx >= (unsigned)NBX) continue;
                int bin = by * NBX + bx;
                unsigned cnt = (cntp[bin >> 2] >> ((unsigned)(bin & 3) * 8u)) & 0xFFu;
                if (cnt > K) cnt = K;
                for (unsigned j = 0; j < cnt; ++j) {
                    int id = bins[bin * K + j];
                    int ppy = id / TS, ppx = id - ppy * TS;
                    int gy = ty0 + ppy, gx = tx0 + ppx;
                    float2 f = flp[gy * W_ + gx];
                    float xf = (float)gx + f.x;
                    float yf = (float)gy + f.y;
                    float fx = xf - floorf(xf);
                    float fy = yf - floorf(yf);
                    float wgt = (bxo ? fx : 1.0f - fx) * (a ? fy : 1.0f - fy);
                    const float* ip = imp + (size_t)gy * W_ + gx;
                    s0 += ip[0]          * wgt;
                    s1 += ip[HW_]        * wgt;
                    s2 += ip[2 * HW_]    * wgt;
                    s3 += ip[3 * HW_]    * wgt;
                }
            }
        }
        int gy = ty0 - R + wy, gx = tx0 - R + wx;
        bool core = (wy >= R) && (wy < TS + R) && (wx >= R) && (wx < TS + R);
        if (core) {
            if (gx < W_) {                      // gy in range by construction
                size_t o = (size_t)gy * W_ + gx;
                outp[o]                   = s0;
                outp[(size_t)HW_ + o]     = s1;
                outp[2 * (size_t)HW_ + o] = s2;
                outp[3 * (size_t)HW_ + o] = s3;
            }
        } else {
            int hc = halo_cell(wy, wx);
            bufp[hc]                                   = s0;
            bufp[(size_t)NTILES * HALO_CELLS + hc]     = s1;
            bufp[2 * (size_t)NTILES * HALO_CELLS + hc] = s2;
            bufp[3 * (size_t)NTILES * HALO_CELLS + hc] = s3;
        }
    }
}

// Halo-gather: each ring pixel sums the <=3 neighbor-tile halo cells covering
// it. Parallel over (pixel, channel-group).
__global__ __launch_bounds__(256)
void fw_warp_hgather(const float* __restrict__ buf, float* __restrict__ out) {
    int t = blockIdx.x * 256 + threadIdx.x;
    const int total = B_ * HW_;
    if (t >= total * NCG) return;
    int cgi = t / total;            // consecutive t -> same cgi, consecutive pix
    int pix = t - cgi * total;
    int x = pix % W_;
    int r = pix / W_;
    int y = r % H_;
    int b = r / H_;
    int tx = x / TS, ty = y / TS;
    int px = x - tx * TS, py = y - ty * TS;
    bool rl = px < R, rr = px >= TS - R;
    bool rt = py < R, rb = py >= TS - R;
    if (!(rl | rr | rt | rb)) return;

    int dx = rl ? -1 : (rr ? 1 : 0);
    int dy = rt ? -1 : (rb ? 1 : 0);

    int t_h = -1, c_h = 0, t_v = -1, c_v = 0, t_d = -1, c_d = 0;
    if (dx) {
        int ntx = tx + dx;
        if ((unsigned)ntx < TILES_X) {
            t_h = ty * TILES_X + ntx;
            c_h = halo_cell(y - (ty * TS - R), x - (ntx * TS - R));
        }
    }
    if (dy) {
        int nty = ty + dy;
        if ((unsigned)nty < TILES_Y) {
            t_v = nty * TILES_X + tx;
            c_v = halo_cell(y - (nty * TS - R), x - (tx * TS - R));
        }
    }
    if (dx && dy) {
        int ntx = tx + dx, nty = ty + dy;
        if ((unsigned)ntx < TILES_X && (unsigned)nty < TILES_Y) {
            t_d = nty * TILES_X + ntx;
            c_d = halo_cell(y - (nty * TS - R), x - (ntx * TS - R));
        }
    }
    if (t_h < 0 && t_v < 0 && t_d < 0) return;

    size_t o = (size_t)y * W_ + x;
    #pragma unroll
    for (int cc = 0; cc < CG; ++cc) {
        int c = cgi * CG + cc;
        size_t cb = (size_t)(b * C_ + c);
        float s = out[cb * HW_ + o];
        if (t_h >= 0) s += buf[(cb * NTILES + t_h) * HALO_CELLS + c_h];
        if (t_v >= 0) s += buf[(cb * NTILES + t_v) * HALO_CELLS + c_v];
        if (t_d >= 0) s += buf[(cb * NTILES + t_d) * HALO_CELLS + c_d];
        out[cb * HW_ + o] = s;
    }
}

// Far kernel: replay pixels whose window predicate failed (native atomics).
__global__ __launch_bounds__(256)
void fw_warp_far(const float* __restrict__ im0,
                 const float* __restrict__ flow,
                 float* __restrict__ out) {
    int tid = blockIdx.x * blockDim.x + threadIdx.x;
    const int total = B_ * HW_;
    if (tid >= total) return;
    int x = tid % W_;
    int t = tid / W_;
    int y = t % H_;
    int b = t / H_;

    float2 f = ((const float2*)flow)[tid];
    float xf = (float)x + f.x;
    float yf = (float)y + f.y;
    float x0f = floorf(xf), y0f = floorf(yf);
    int x0 = (int)x0f, y0 = (int)y0f;
    int tx0 = (x / TS) * TS;
    int ty0 = (y / TS) * TS;
    bool inwin = !(x0 < tx0 - R || x0 > tx0 + TS + R - 2 ||
                   y0 < ty0 - R || y0 > ty0 + TS + R - 2);
    if (inwin) return;   // tiled kernel handled it

    float wx1 = xf - x0f, wx0 = 1.0f - wx1;
    float wy1 = yf - y0f, wy0 = 1.0f - wy1;
    bool xv0 = (unsigned)x0       < (unsigned)W_;
    bool xv1 = (unsigned)(x0 + 1) < (unsigned)W_;
    bool yv0 = (unsigned)y0       < (unsigned)H_;
    bool yv1 = (unsigned)(y0 + 1) < (unsigned)H_;

    for (int c = 0; c < C_; ++c) {
        float v = im0[(size_t)(b * C_ + c) * HW_ + (size_t)y * W_ + x];
        float* op = out + (size_t)(b * C_ + c) * HW_;
        if (yv0 && xv0) fadd_glb(&op[(size_t)y0 * W_ + x0],           v * wx0 * wy0);
        if (yv0 && xv1) fadd_glb(&op[(size_t)y0 * W_ + x0 + 1],       v * wx1 * wy0);
        if (yv1 && xv0) fadd_glb(&op[(size_t)(y0 + 1) * W_ + x0],     v * wx0 * wy1);
        if (yv1 && xv1) fadd_glb(&op[(size_t)(y0 + 1) * W_ + x0 + 1], v * wx1 * wy1);
    }
}

// Replay kernel: bin-overflow pixels, per (pixel, cg) entry; native atomics.
// Runs LAST (after all plain stores and halo-gather RMW).
__global__ __launch_bounds__(256)
void fw_warp_replay(const float* __restrict__ im0,
                    const float* __restrict__ flow,
                    float* __restrict__ out,
                    const unsigned* __restrict__ ovctr,
                    const unsigned* __restrict__ ovlist,
                    unsigned cap) {
    unsigned n = *ovctr;
    if (n > cap) n = cap;
    unsigned t = blockIdx.x * 256 + threadIdx.x;
    if (t >= n) return;
    unsigned e = ovlist[t];
    int cg = (int)(e >> 24);
    unsigned gid = e & 0xFFFFFFu;
    int b = gid / HW_;
    int rem = gid - b * HW_;
    int y = rem / W_, x = rem - (rem / W_) * W_;

    float2 f = ((const float2*)flow)[gid];
    float xf = (float)x + f.x;
    float yf = (float)y + f.y;
    float x0f = floorf(xf), y0f = floorf(yf);
    int x0 = (int)x0f, y0 = (int)y0f;
    float wx1 = xf - x0f, wx0 = 1.0f - wx1;
    float wy1 = yf - y0f, wy0 = 1.0f - wy1;
    bool xv0 = (unsigned)x0       < (unsigned)W_;
    bool xv1 = (unsigned)(x0 + 1) < (unsigned)W_;
    bool yv0 = (unsigned)y0       < (unsigned)H_;
    bool yv1 = (unsigned)(y0 + 1) < (unsigned)H_;

    for (int cc = 0; cc < CG; ++cc) {
        int c = cg * CG + cc;
        float v = im0[(size_t)(b * C_ + c) * HW_ + (size_t)y * W_ + x];
        float* op = out + (size_t)(b * C_ + c) * HW_;
        if (yv0 && xv0) fadd_glb(&op[(size_t)y0 * W_ + x0],           v * wx0 * wy0);
        if (yv0 && xv1) fadd_glb(&op[(size_t)y0 * W_ + x0 + 1],       v * wx1 * wy0);
        if (yv1 && xv0) fadd_glb(&op[(size_t)(y0 + 1) * W_ + x0],     v * wx0 * wy1);
        if (yv1 && xv1) fadd_glb(&op[(size_t)(y0 + 1) * W_ + x0 + 1], v * wx1 * wy1);
    }
}

// Legacy fallback (ws too small): direct LDS fp-atomic splat + atomic ring
// flush (round-2 structure). Correct but slow; out must be pre-zeroed.
__global__ __launch_bounds__(NT1)
void fw_warp_legacy(const float* __restrict__ im0,
                    const float* __restrict__ flow,
                    float* __restrict__ out) {
    __shared__ float acc[CG * WIN * WIN];
    const int cg = blockIdx.x, tI = blockIdx.y, b = blockIdx.z;
    const int tx0 = (tI % TILES_X) * TS;
    const int ty0 = (tI / TILES_X) * TS;
    const int tid = threadIdx.x;
    for (int i = tid; i < CG * WIN * WIN; i += NT1) acc[i] = 0.0f;
    __syncthreads();
    const float*  imp = im0 + (size_t)(b * C_ + cg * CG) * HW_;
    const float2* flp = (const float2*)flow + (size_t)b * HW_;
    for (int i = tid; i < TS * TS; i += NT1) {
        int py = i / TS, px = i - py * TS;
        int y = ty0 + py, x = tx0 + px;
        if (x >= W_) continue;
        float2 f = flp[y * W_ + x];
        float xf = (float)x + f.x, yf = (float)y + f.y;
        float x0f = floorf(xf), y0f = floorf(yf);
        int x0 = (int)x0f, y0 = (int)y0f;
        if (x0 < tx0 - R || x0 > tx0 + TS + R - 2 ||
            y0 < ty0 - R || y0 > ty0 + TS + R - 2) continue;
        float wx1 = xf - x0f, wx0 = 1.0f - wx1;
        float wy1 = yf - y0f, wy0 = 1.0f - wy1;
        float w00 = wx0 * wy0, w10 = wx1 * wy0;
        float w01 = wx0 * wy1, w11 = wx1 * wy1;
        const float* ip = imp + (size_t)y * W_ + x;
        int lx = x0 - (tx0 - R), ly = y0 - (ty0 - R);
        float* p = &acc[ly * WIN + lx];
        #pragma unroll
        for (int cc = 0; cc < CG; ++cc) {
            float v = ip[cc * HW_];
            atomicAdd(p,           v * w00);
            atomicAdd(p + 1,       v * w10);
            atomicAdd(p + WIN,     v * w01);
            atomicAdd(p + WIN + 1, v * w11);
            p += WIN * WIN;
        }
    }
    __syncthreads();
    float* outp = out + (size_t)(b * C_ + cg * CG) * HW_;
    for (int i = tid; i < WIN * WIN; i += NT1) {
        int wy = i / WIN, wx = i - wy * WIN;
        int gy = ty0 - R + wy, gx = tx0 - R + wx;
        if ((unsigned)gy < (unsigned)H_ && (unsigned)gx < (unsigned)W_) {
            bool interior = (wy >= 2 * R) && (wy < TS) && (wx >= 2 * R) && (wx < TS);
            size_t o = (size_t)gy * W_ + gx;
            #pragma unroll
            for (int c = 0; c < CG; ++c) {
                float v = acc[c * WIN * WIN + i];
                if (interior)          outp[(size_t)c * HW_ + o] = v;
                else if (v != 0.0f)    fadd_glb(&outp[(size_t)c * HW_ + o], v);
            }
        }
    }
}

extern "C" void kernel_launch(void* const* d_in, const int* in_sizes, int n_in,
                              void* d_out, int out_size, void* d_ws, size_t ws_size,
                              hipStream_t stream) {
    const float* im0  = (const float*)d_in[0];
    const float* flow = (const float*)d_in[1];
    float* out = (float*)d_out;

    const size_t HALO_BYTES = (size_t)B_ * C_ * NTILES * HALO_CELLS * sizeof(float); // 95.2 MB
    const int totalPix = B_ * HW_;
    dim3 grid1(NCG, NTILES, B_);

    const unsigned CAP_BIG = 262144, CAP_SMALL = 16384;
    unsigned cap = 0;
    if (d_ws && ws_size >= HALO_BYTES + 64 + CAP_BIG * 4)        cap = CAP_BIG;
    else if (d_ws && ws_size >= HALO_BYTES + 64 + CAP_SMALL * 4) cap = CAP_SMALL;

    if (cap) {
        unsigned* ovctr  = (unsigned*)((char*)d_ws + HALO_BYTES);
        unsigned* ovlist = ovctr + 16;
        hipMemsetAsync(ovctr, 0, sizeof(unsigned), stream);
        fw_warp_bin<<<grid1, NT1, 0, stream>>>(im0, flow, out, (float*)d_ws,
                                               ovctr, ovlist, cap);
        fw_warp_hgather<<<(totalPix * NCG + 255) / 256, 256, 0, stream>>>(
            (const float*)d_ws, out);
        fw_warp_far<<<(totalPix + 255) / 256, 256, 0, stream>>>(im0, flow, out);
        fw_warp_replay<<<(cap + 255) / 256, 256, 0, stream>>>(im0, flow, out,
                                                              ovctr, ovlist, cap);
    } else {
        hipMemsetAsync(d_out, 0, (size_t)out_size * sizeof(float), stream);
        fw_warp_legacy<<<grid1, NT1, 0, stream>>>(im0, flow, out);
        fw_warp_far<<<(totalPix + 255) / 256, 256, 0, stream>>>(im0, flow, out);
    }
}